// Round 1
// 635.485 us; speedup vs baseline: 1.0073x; 1.0073x over previous
//
#include <hip/hip_runtime.h>

typedef __bf16 bf16;
typedef __bf16 bf16x8 __attribute__((ext_vector_type(8)));
typedef float  f32x4  __attribute__((ext_vector_type(4)));

#define C_    384
#define V_    32768
#define NTOT  12582912.0f   // 384*32768 elements per batch for GroupNorm
#define EPS_  1e-5f
#define WMAT  147456        // 384*384

// ---- async global->LDS, 16B per lane (per-lane global src address is legal) ----
__device__ __forceinline__ void g2l16(const void* g, void* l) {
    __builtin_amdgcn_global_load_lds(
        (const __attribute__((address_space(1))) void*)g,
        (__attribute__((address_space(3))) void*)l, 16, 0, 0);
}

// NaN-safe tanh-approx GELU: x * 0.5*(1+tanh(t)) = x / (1 + exp(-2t))
__device__ __forceinline__ float gelu_t(float x) {
    float u = -1.5957691216f * x * (1.0f + 0.044715f * x * x);
    return x / (1.0f + __expf(u));
}

__device__ __forceinline__ float wave_sum(float v) {
#pragma unroll
    for (int off = 32; off > 0; off >>= 1) v += __shfl_down(v, off, 64);
    return v;
}

// =================== P1: weights fp32 -> bf16 (w1,w21,w22,w23) ===================
__global__ void k_wcast(const float* __restrict__ w1, const float* __restrict__ w21,
                        const float* __restrict__ w22, const float* __restrict__ w23,
                        bf16* __restrict__ wb) {
    int i = (blockIdx.x * 256 + threadIdx.x) * 4;
    const float* srcs[4] = {w1, w21, w22, w23};
    int t = i / WMAT;
    int j = i - t * WMAT;
    const float4 v = *(const float4*)(srcs[t] + j);
    bf16* d = wb + i;
    d[0] = (bf16)v.x; d[1] = (bf16)v.y; d[2] = (bf16)v.z; d[3] = (bf16)v.w;
}

// =================== P2: x [b][c][v] fp32 -> xb [b][v][c] bf16 ===================
__global__ void k_txp(const float* __restrict__ x, bf16* __restrict__ xb) {
    __shared__ float tile[32][65];
    int bid = blockIdx.x;                   // 2 * 512 * 12
    int cb = bid % 12;
    int vb = (bid / 12) & 511;
    int b  = bid / (12 * 512);
    int c0 = cb * 32, v0 = vb * 64;
    int t = threadIdx.x;
    int vl = t & 63, cl = t >> 6;
    const float* src = x + ((size_t)(b * C_ + c0)) * V_ + v0;
#pragma unroll
    for (int i = 0; i < 8; i++)
        tile[cl + i * 4][vl] = src[(size_t)(cl + i * 4) * V_ + vl];
    __syncthreads();
    int vl2 = t >> 2, cl2 = (t & 3) * 8;
    bf16x8 o;
#pragma unroll
    for (int j = 0; j < 8; j++) o[j] = (bf16)tile[cl2 + j][vl2];
    *(bf16x8*)(xb + ((size_t)(b * V_ + v0 + vl2)) * C_ + c0 + cl2) = o;
}

// XCD-aware tile map: bid&7 ~ XCD; each XCD owns a contiguous 64-m-tile range,
// n fastest so the 3 n-blocks of one m-tile are temporally adjacent on one XCD.
__device__ __forceinline__ void tile_coords(int bid, int& b, int& m0, int& n0) {
    int x = bid & 7, gq = bid >> 3;        // gq in [0,192)
    n0 = (gq % 3) * 128;
    int mt = x * 64 + gq / 3;              // 512 m-tiles (2 batches x 256)
    b  = mt >> 8;
    m0 = (mt & 255) * 128;
}

#define ZERO_ACC(acc) \
    _Pragma("unroll") for (int i = 0; i < 4; i++) \
    _Pragma("unroll") for (int j = 0; j < 4; j++) \
    _Pragma("unroll") for (int r = 0; r < 4; r++) acc[i][j][r] = 0.f;

// =================== Pipelined MFMA GEMM core: 128x128 tile, K=384, BK=64 ============
// Double-buffered LDS (2 x 16KB per operand). Per K-step: issue next-step
// global_load_lds into buf[nxt], compute buf[cur] (ds_read+MFMA overlaps the load
// latency), then ONE __syncthreads() whose implicit vmcnt(0) drain retires the
// prefetch. Depth-1 pipeline == the verified plain-HIP 2-phase template.
// LDS row-major [128 rows][64 ch]; 16B chunk c of row r holds global chunk c^(r&7).
__device__ __forceinline__ void gemm_pipe(const bf16* __restrict__ A, const bf16* __restrict__ Bw,
                                          bf16* sA, bf16* sB, f32x4 acc[4][4]) {
    const int tid  = threadIdx.x;
    const int lane = tid & 63;
    const int wv   = tid >> 6;
    const int wm   = (wv & 1) * 64, wn = (wv >> 1) * 64;
    const int lrow = lane & 15;
    const int q    = lane >> 4;
    const int row_l = tid >> 3;
    const int kcs   = (tid & 7) ^ (row_l & 7);
    const bf16* ga = A  + row_l * C_ + kcs * 8;
    const bf16* gb = Bw + row_l * C_ + kcs * 8;
    char* la = (char*)sA + tid * 16;
    char* lb = (char*)sB + tid * 16;
    const char* ra = (const char*)sA;
    const char* rb = (const char*)sB;
    // prologue: stage K-step 0 into buffer 0
#pragma unroll
    for (int j = 0; j < 4; j++) {
        g2l16(ga + j * 32 * C_, la + j * 4096);
        g2l16(gb + j * 32 * C_, lb + j * 4096);
    }
    __syncthreads();
#pragma unroll
    for (int s = 0; s < 6; s++) {
        const int cur = (s & 1) * 16384, nxt = 16384 - cur;
        if (s < 5) {
            int off = (s + 1) * 64;
#pragma unroll
            for (int j = 0; j < 4; j++) {
                g2l16(ga + off + j * 32 * C_, la + nxt + j * 4096);
                g2l16(gb + off + j * 32 * C_, lb + nxt + j * 4096);
            }
        }
#pragma unroll
        for (int t = 0; t < 2; t++) {
            bf16x8 af[4], bfr[4];
#pragma unroll
            for (int i = 0; i < 4; i++) {
                int r = wm + i * 16 + lrow;
                af[i] = *(const bf16x8*)(ra + cur + r * 128 + (((t * 4 + q) ^ (r & 7)) * 16));
            }
#pragma unroll
            for (int i = 0; i < 4; i++) {
                int r = wn + i * 16 + lrow;
                bfr[i] = *(const bf16x8*)(rb + cur + r * 128 + (((t * 4 + q) ^ (r & 7)) * 16));
            }
#pragma unroll
            for (int mi = 0; mi < 4; mi++)
#pragma unroll
                for (int ni = 0; ni < 4; ni++)
                    acc[mi][ni] = __builtin_amdgcn_mfma_f32_16x16x32_bf16(
                        af[mi], bfr[ni], acc[mi][ni], 0, 0, 0);
        }
        if (s < 5) __syncthreads();
    }
}

// =================== P3: GEMM1 = xb @ w1 + b1 -> h1 bf16, + GN1 stats ===================
__global__ __launch_bounds__(256, 2) void k_gemm1(const bf16* __restrict__ xb, const bf16* __restrict__ w1b,
                                                  const float* __restrict__ b1, bf16* __restrict__ h1,
                                                  float* __restrict__ stats) {
    __shared__ bf16 sA[2 * 128 * 64], sB[2 * 128 * 64];
    int b, m0, n0; tile_coords(blockIdx.x, b, m0, n0);
    f32x4 acc[4][4];
    ZERO_ACC(acc)
    gemm_pipe(xb + ((size_t)(b * V_) + m0) * C_, w1b + n0 * C_, sA, sB, acc);
    int lane = threadIdx.x & 63, wv = threadIdx.x >> 6;
    int wm = (wv & 1) * 64, wn = (wv >> 1) * 64;
    int col = lane & 15, rowq = (lane >> 4) * 4;
    float s = 0.f, ss = 0.f;
#pragma unroll
    for (int ni = 0; ni < 4; ni++) {
        int o = n0 + wn + ni * 16 + col;
        float bias = b1[o];
#pragma unroll
        for (int mi = 0; mi < 4; mi++) {
            size_t vb = (size_t)(b * V_) + m0 + wm + mi * 16 + rowq;
#pragma unroll
            for (int rg = 0; rg < 4; rg++) {
                float val = acc[mi][ni][rg] + bias;
                s += val; ss += val * val;
                h1[(vb + rg) * C_ + o] = (bf16)val;
            }
        }
    }
    s = wave_sum(s); ss = wave_sum(ss);
    if (lane == 0) { atomicAdd(&stats[2 * b], s); atomicAdd(&stats[2 * b + 1], ss); }
}

// =================== P4: GN1 + GELU -> g ===================
__global__ void k_act(const bf16* __restrict__ h1, const float* __restrict__ g1,
                      const float* __restrict__ bt1, const float* __restrict__ stats,
                      bf16* __restrict__ g) {
    int idx = blockIdx.x * 256 + threadIdx.x;   // 2*32768*48 threads
    int cg = idx % 48;
    int t2 = idx / 48;
    int v = t2 & (V_ - 1);
    int b = t2 >> 15;
    float inv  = 1.0f / NTOT;
    float mean = stats[2 * b] * inv;
    float var  = stats[2 * b + 1] * inv - mean * mean;
    float rstd = rsqrtf(var + EPS_);
    int c0 = cg * 8;
    float a[8], be[8];
    {
        const float4 gA = *(const float4*)(g1 + c0);
        const float4 gB = *(const float4*)(g1 + c0 + 4);
        const float4 bA = *(const float4*)(bt1 + c0);
        const float4 bB = *(const float4*)(bt1 + c0 + 4);
        float gg[8] = {gA.x, gA.y, gA.z, gA.w, gB.x, gB.y, gB.z, gB.w};
        float bb[8] = {bA.x, bA.y, bA.z, bA.w, bB.x, bB.y, bB.z, bB.w};
#pragma unroll
        for (int e = 0; e < 8; e++) { a[e] = rstd * gg[e]; be[e] = bb[e] - mean * a[e]; }
    }
    size_t off = ((size_t)b * V_ + v) * C_ + c0;
    bf16x8 xin = *(const bf16x8*)(h1 + off);
    bf16x8 outv;
#pragma unroll
    for (int e = 0; e < 8; e++) outv[e] = (bf16)gelu_t((float)xin[e] * a[e] + be[e]);
    *(bf16x8*)(g + off) = outv;
}

// =================== P5: fused GEMM2 (3 shifted branches) + GN2 stats ===================
// One continuous 18-step (3 branches x 6 K-steps) depth-1 pipeline; shifted-A source
// pointers resolved per unrolled step (validity pre-resolved to a zero page).
__global__ __launch_bounds__(256, 2) void k_gemm2(const bf16* __restrict__ g, const bf16* __restrict__ wb,
                                                  const float* __restrict__ b21, const float* __restrict__ b22,
                                                  const float* __restrict__ b23, bf16* __restrict__ y,
                                                  float* __restrict__ stats, const bf16* __restrict__ zp) {
    __shared__ bf16 sA[2 * 128 * 64], sB[2 * 128 * 64];
    int b, m0, n0; tile_coords(blockIdx.x, b, m0, n0);
    const int tid  = threadIdx.x;
    const int lane = tid & 63, wv = tid >> 6;
    const int wm = (wv & 1) * 64, wn = (wv >> 1) * 64;
    const int col = lane & 15, rowq = (lane >> 4) * 4;
    const int lrow = lane & 15;
    const int q    = lane >> 4;
    const int row_l = tid >> 3;
    const int kcs   = (tid & 7) ^ (row_l & 7);
    const int d0 = m0 >> 10;
    const bf16* gA = g + ((size_t)(b * V_) + m0) * C_;
    const bf16* pc[4];
#pragma unroll
    for (int j = 0; j < 4; j++) pc[j] = gA + (row_l + j * 32) * C_ + kcs * 8;
    const bf16* gb0 = wb + n0 * C_ + row_l * C_ + kcs * 8;
    char* la = (char*)sA + tid * 16;
    char* lb = (char*)sB + tid * 16;
    const char* ra = (const char*)sA;
    const char* rb = (const char*)sB;

    // shifted-A row pointer for step st (ax=st/6, K-group s=st%6), chunk j.
    // s<2 -> +shift group, 2<=s<4 -> center, s>=4 -> -shift group.
    auto aptr = [&](int st, int j) -> const bf16* {
        int ax = st / 6, s = st - ax * 6;
        const bf16* p = pc[j];
        if (s < 2) {
            if (ax == 0)      { int hh = ((m0 >> 5) + j) & 31; p = (hh < 31) ? p + 32 * C_ : zp; }
            else if (ax == 1) { p = (d0 < 31) ? p + 1024 * C_ : zp; }
            else              { p = (row_l < 31) ? p + C_ : zp; }
        } else if (s >= 4) {
            if (ax == 0)      { int hh = ((m0 >> 5) + j) & 31; p = (hh > 0) ? p - 32 * C_ : zp; }
            else if (ax == 1) { p = (d0 > 0) ? p - 1024 * C_ : zp; }
            else              { p = (row_l > 0) ? p - C_ : zp; }
        }
        return p + s * 64;
    };
    auto stage2 = [&](int st, int buf) {
        int ax = st / 6, s = st - ax * 6;
#pragma unroll
        for (int j = 0; j < 4; j++) {
            g2l16(aptr(st, j), la + buf + j * 4096);
            g2l16(gb0 + (ax + 1) * WMAT + s * 64 + j * 32 * C_, lb + buf + j * 4096);
        }
    };

    f32x4 yac[4][4];
    ZERO_ACC(yac)
    f32x4 acc[4][4];
    ZERO_ACC(acc)

    stage2(0, 0);
    __syncthreads();
#pragma unroll
    for (int st = 0; st < 18; st++) {
        const int cur = (st & 1) * 16384, nxt = 16384 - cur;
        if (st < 17) stage2(st + 1, nxt);
#pragma unroll
        for (int t = 0; t < 2; t++) {
            bf16x8 af[4], bfr[4];
#pragma unroll
            for (int i = 0; i < 4; i++) {
                int r = wm + i * 16 + lrow;
                af[i] = *(const bf16x8*)(ra + cur + r * 128 + (((t * 4 + q) ^ (r & 7)) * 16));
            }
#pragma unroll
            for (int i = 0; i < 4; i++) {
                int r = wn + i * 16 + lrow;
                bfr[i] = *(const bf16x8*)(rb + cur + r * 128 + (((t * 4 + q) ^ (r & 7)) * 16));
            }
#pragma unroll
            for (int mi = 0; mi < 4; mi++)
#pragma unroll
                for (int ni = 0; ni < 4; ni++)
                    acc[mi][ni] = __builtin_amdgcn_mfma_f32_16x16x32_bf16(
                        af[mi], bfr[ni], acc[mi][ni], 0, 0, 0);
        }
        if ((st % 6) == 5) {               // end of a branch: fold GELU into yac (regs only)
            int ax = st / 6;
            const float* bs = (ax == 0) ? b21 : (ax == 1) ? b22 : b23;
#pragma unroll
            for (int ni = 0; ni < 4; ni++) {
                float bias = bs[n0 + wn + ni * 16 + col];
#pragma unroll
                for (int mi = 0; mi < 4; mi++)
#pragma unroll
                    for (int rg = 0; rg < 4; rg++) {
                        yac[mi][ni][rg] += gelu_t(acc[mi][ni][rg] + bias);
                        acc[mi][ni][rg] = 0.f;
                    }
            }
        }
        if (st < 17) __syncthreads();
    }

    float s = 0.f, ss = 0.f;
#pragma unroll
    for (int ni = 0; ni < 4; ni++) {
        int o = n0 + wn + ni * 16 + col;
#pragma unroll
        for (int mi = 0; mi < 4; mi++) {
            size_t vb = (size_t)(b * V_) + m0 + wm + mi * 16 + rowq;
#pragma unroll
            for (int rg = 0; rg < 4; rg++) {
                float val = yac[mi][ni][rg];
                s += val; ss += val * val;
                y[(vb + rg) * C_ + o] = (bf16)val;
            }
        }
    }
    s = wave_sum(s); ss = wave_sum(ss);
    if (lane == 0) { atomicAdd(&stats[4 + 2 * b], s); atomicAdd(&stats[5 + 2 * b], ss); }
}

// =================== P6: fold GN2 affine into W3/b3 (per batch) ===================
__global__ void k_fold(const float* __restrict__ w3, const float* __restrict__ b3,
                       const float* __restrict__ g2, const float* __restrict__ bt2,
                       const float* __restrict__ stats, bf16* __restrict__ w3p,
                       float* __restrict__ b3p) {
    int bo = blockIdx.x;           // 768 = 2*384
    int b = bo / 384, o = bo % 384;
    int l = threadIdx.x;           // 64 threads
    float inv  = 1.0f / NTOT;
    float mean = stats[4 + 2 * b] * inv;
    float var  = stats[5 + 2 * b] * inv - mean * mean;
    float rstd = rsqrtf(var + EPS_);
    float part = 0.f;
    for (int c = l; c < C_; c += 64) {
        float wv_ = w3[o * C_ + c];
        float gr  = g2[c] * rstd;
        w3p[(size_t)b * WMAT + o * C_ + c] = (bf16)(wv_ * gr);
        part += wv_ * (bt2[c] - mean * gr);
    }
    part = wave_sum(part);
    if (l == 0) b3p[bo] = b3[o] + part;
}

// =================== P7: GEMM3 -> d_out fp32, channel-first layout ===================
__global__ __launch_bounds__(256, 2) void k_gemm3(const bf16* __restrict__ y, const bf16* __restrict__ w3p,
                                                  const float* __restrict__ b3p, float* __restrict__ out) {
    __shared__ bf16 sA[2 * 128 * 64], sB[2 * 128 * 64];
    int b, m0, n0; tile_coords(blockIdx.x, b, m0, n0);
    f32x4 acc[4][4];
    ZERO_ACC(acc)
    gemm_pipe(y + ((size_t)(b * V_) + m0) * C_, w3p + (size_t)b * WMAT + n0 * C_, sA, sB, acc);
    int lane = threadIdx.x & 63, wv = threadIdx.x >> 6;
    int wm = (wv & 1) * 64, wn = (wv >> 1) * 64;
    int col = lane & 15, rowq = (lane >> 4) * 4;
#pragma unroll
    for (int ni = 0; ni < 4; ni++) {
        int o = n0 + wn + ni * 16 + col;
        float bias = b3p[b * C_ + o];
#pragma unroll
        for (int mi = 0; mi < 4; mi++) {
            f32x4 r = acc[mi][ni];
            r[0] += bias; r[1] += bias; r[2] += bias; r[3] += bias;
            size_t adr = (size_t)b * ((size_t)C_ * V_) + (size_t)o * V_ + (m0 + wm + mi * 16 + rowq);
            *(f32x4*)(out + adr) = r;
        }
    }
}

extern "C" void kernel_launch(void* const* d_in, const int* in_sizes, int n_in,
                              void* d_out, int out_size, void* d_ws, size_t ws_size,
                              hipStream_t stream) {
    const float* x   = (const float*)d_in[0];
    const float* w1  = (const float*)d_in[1];
    const float* b1  = (const float*)d_in[2];
    const float* g1  = (const float*)d_in[3];
    const float* bt1 = (const float*)d_in[4];
    const float* w21 = (const float*)d_in[5];
    const float* b21 = (const float*)d_in[6];
    const float* w22 = (const float*)d_in[7];
    const float* b22 = (const float*)d_in[8];
    const float* w23 = (const float*)d_in[9];
    const float* b23 = (const float*)d_in[10];
    const float* g2  = (const float*)d_in[11];
    const float* bt2 = (const float*)d_in[12];
    const float* w3  = (const float*)d_in[13];
    const float* b3  = (const float*)d_in[14];
    float* out = (float*)d_out;

    char* ws = (char*)d_ws;
    const size_t HALF = 50331648ull;                    // one bf16 tensor (2*384*32768*2 B)
    bf16*  xb  = (bf16*)ws;                             // xb (P2-P3), then y (P5-P7)
    bf16*  g   = (bf16*)(ws + HALF);
    char*  tail = ws + 2 * HALF;
    float* stats = (float*)tail;                        // tail[0:128)   zeroed
    bf16*  zp    = (bf16*)(tail + 2048);                // tail[2048:4096) zeroed
    bf16*  wb    = (bf16*)(tail + 4096);                // 1,179,648 B
    bf16*  w3p   = (bf16*)(tail + 4096 + 1179648);      //   589,824 B
    float* b3p   = (float*)(tail + 4096 + 1179648 + 589824);
    bf16*  h1 = (bf16*)d_out;                           // d_out first half as scratch (dead before P7)
    bf16*  y  = xb;

    hipMemsetAsync(tail, 0, 4096, stream);              // stats + zero page
    k_wcast<<<576,   256, 0, stream>>>(w1, w21, w22, w23, wb);
    k_txp  <<<12288, 256, 0, stream>>>(x, xb);
    k_gemm1<<<1536,  256, 0, stream>>>(xb, wb, b1, h1, stats);
    k_act  <<<12288, 256, 0, stream>>>(h1, g1, bt1, stats, g);
    k_gemm2<<<1536,  256, 0, stream>>>(g, wb, b21, b22, b23, y, stats, zp);
    k_fold <<<768,    64, 0, stream>>>(w3, b3, g2, bt2, stats, w3p, b3p);
    k_gemm3<<<1536,  256, 0, stream>>>(y, w3p, b3p, out);
}

// Round 3
// 626.962 us; speedup vs baseline: 1.0210x; 1.0136x over previous
//
#include <hip/hip_runtime.h>

typedef __bf16 bf16;
typedef __bf16 bf16x8 __attribute__((ext_vector_type(8)));
typedef float  f32x4  __attribute__((ext_vector_type(4)));

#define C_    384
#define V_    32768
#define NTOT  12582912.0f   // 384*32768 elements per batch for GroupNorm
#define EPS_  1e-5f
#define WMAT  147456        // 384*384

// ---- async global->LDS, 16B per lane (per-lane global src address is legal) ----
__device__ __forceinline__ void g2l16(const void* g, void* l) {
    __builtin_amdgcn_global_load_lds(
        (const __attribute__((address_space(1))) void*)g,
        (__attribute__((address_space(3))) void*)l, 16, 0, 0);
}

// NaN-safe tanh-approx GELU: x * 0.5*(1+tanh(t)) = x / (1 + exp(-2t))
__device__ __forceinline__ float gelu_t(float x) {
    float u = -1.5957691216f * x * (1.0f + 0.044715f * x * x);
    return x / (1.0f + __expf(u));
}

__device__ __forceinline__ float wave_sum(float v) {
#pragma unroll
    for (int off = 32; off > 0; off >>= 1) v += __shfl_down(v, off, 64);
    return v;
}

// =================== P1: weights fp32 -> bf16 (w1,w21,w22,w23) ===================
__global__ void k_wcast(const float* __restrict__ w1, const float* __restrict__ w21,
                        const float* __restrict__ w22, const float* __restrict__ w23,
                        bf16* __restrict__ wb) {
    int i = (blockIdx.x * 256 + threadIdx.x) * 4;
    const float* srcs[4] = {w1, w21, w22, w23};
    int t = i / WMAT;
    int j = i - t * WMAT;
    const float4 v = *(const float4*)(srcs[t] + j);
    bf16* d = wb + i;
    d[0] = (bf16)v.x; d[1] = (bf16)v.y; d[2] = (bf16)v.z; d[3] = (bf16)v.w;
}

// =================== P2: x [b][c][v] fp32 -> xb [b][v][c] bf16 ===================
__global__ void k_txp(const float* __restrict__ x, bf16* __restrict__ xb) {
    __shared__ float tile[32][65];
    int bid = blockIdx.x;                   // 2 * 512 * 12
    int cb = bid % 12;
    int vb = (bid / 12) & 511;
    int b  = bid / (12 * 512);
    int c0 = cb * 32, v0 = vb * 64;
    int t = threadIdx.x;
    int vl = t & 63, cl = t >> 6;
    const float* src = x + ((size_t)(b * C_ + c0)) * V_ + v0;
#pragma unroll
    for (int i = 0; i < 8; i++)
        tile[cl + i * 4][vl] = src[(size_t)(cl + i * 4) * V_ + vl];
    __syncthreads();
    int vl2 = t >> 2, cl2 = (t & 3) * 8;
    bf16x8 o;
#pragma unroll
    for (int j = 0; j < 8; j++) o[j] = (bf16)tile[cl2 + j][vl2];
    *(bf16x8*)(xb + ((size_t)(b * V_ + v0 + vl2)) * C_ + c0 + cl2) = o;
}

// XCD-aware tile map: bid&7 ~ XCD; each XCD owns a contiguous 64-m-tile range,
// n fastest so the 3 n-blocks of one m-tile are temporally adjacent on one XCD.
__device__ __forceinline__ void tile_coords(int bid, int& b, int& m0, int& n0) {
    int x = bid & 7, gq = bid >> 3;        // gq in [0,192)
    n0 = (gq % 3) * 128;
    int mt = x * 64 + gq / 3;              // 512 m-tiles (2 batches x 256)
    b  = mt >> 8;
    m0 = (mt & 255) * 128;
}

#define ZERO_ACC(acc) \
    _Pragma("unroll") for (int i = 0; i < 4; i++) \
    _Pragma("unroll") for (int j = 0; j < 4; j++) \
    _Pragma("unroll") for (int r = 0; r < 4; r++) acc[i][j][r] = 0.f;

// ---- counted waits + barrier-with-compiler-fence (T3/T4: never drain vmcnt to 0
// in the loop). s_barrier is emitted via asm with a "memory" clobber so the
// compiler cannot hoist the next step's global_load_lds issues above it (the
// builtin has no fence semantics -> would race on the double buffer).
#define VMCNT8() asm volatile("s_waitcnt vmcnt(8)" ::: "memory")
#define VMCNT0() asm volatile("s_waitcnt vmcnt(0)" ::: "memory")
#define BAR()    asm volatile("s_barrier" ::: "memory")

// =================== Pipelined MFMA GEMM core: 128x128 tile, K=384, BK=64 ============
// Double-buffered LDS (2 x 16KB per operand). Per K-step:
//   issue 8 prefetch loads into buf[nxt]  (vmcnt += 8)
//   s_waitcnt vmcnt(8)  -> previous step's 8 loads (buf[cur]) have landed,
//                          the new 8 stay in flight across the barrier
//   s_barrier           -> all waves' cur-data visible
//   ds_read(cur) + MFMA (load latency of nxt hides under this)
//   s_barrier           -> all waves done reading cur before it is overwritten
// LDS row-major [128 rows][64 ch]; 16B chunk c of row r holds global chunk c^(r&7).
__device__ __forceinline__ void gemm_pipe(const bf16* __restrict__ A, const bf16* __restrict__ Bw,
                                          bf16* sA, bf16* sB, f32x4 acc[4][4]) {
    const int tid  = threadIdx.x;
    const int lane = tid & 63;
    const int wv   = tid >> 6;
    const int wm   = (wv & 1) * 64, wn = (wv >> 1) * 64;
    const int lrow = lane & 15;
    const int q    = lane >> 4;
    const int row_l = tid >> 3;
    const int kcs   = (tid & 7) ^ (row_l & 7);
    const bf16* ga = A  + row_l * C_ + kcs * 8;
    const bf16* gb = Bw + row_l * C_ + kcs * 8;
    char* la = (char*)sA + tid * 16;
    char* lb = (char*)sB + tid * 16;
    const char* ra = (const char*)sA;
    const char* rb = (const char*)sB;
    // prologue: stage K-step 0 into buffer 0 (8 loads in flight)
#pragma unroll
    for (int j = 0; j < 4; j++) {
        g2l16(ga + j * 32 * C_, la + j * 4096);
        g2l16(gb + j * 32 * C_, lb + j * 4096);
    }
#pragma unroll
    for (int s = 0; s < 6; s++) {
        const int cur = (s & 1) * 16384, nxt = 16384 - cur;
        if (s < 5) {
            int off = (s + 1) * 64;
#pragma unroll
            for (int j = 0; j < 4; j++) {
                g2l16(ga + off + j * 32 * C_, la + nxt + j * 4096);
                g2l16(gb + off + j * 32 * C_, lb + nxt + j * 4096);
            }
            VMCNT8();
        } else {
            VMCNT0();
        }
        BAR();
#pragma unroll
        for (int t = 0; t < 2; t++) {
            bf16x8 af[4], bfr[4];
#pragma unroll
            for (int i = 0; i < 4; i++) {
                int r = wm + i * 16 + lrow;
                af[i] = *(const bf16x8*)(ra + cur + r * 128 + (((t * 4 + q) ^ (r & 7)) * 16));
            }
#pragma unroll
            for (int i = 0; i < 4; i++) {
                int r = wn + i * 16 + lrow;
                bfr[i] = *(const bf16x8*)(rb + cur + r * 128 + (((t * 4 + q) ^ (r & 7)) * 16));
            }
#pragma unroll
            for (int mi = 0; mi < 4; mi++)
#pragma unroll
                for (int ni = 0; ni < 4; ni++)
                    acc[mi][ni] = __builtin_amdgcn_mfma_f32_16x16x32_bf16(
                        af[mi], bfr[ni], acc[mi][ni], 0, 0, 0);
        }
        if (s < 5) BAR();
    }
}

// =================== P3: GEMM1 = xb @ w1 + b1 -> h1 bf16, + GN1 stats ===================
__global__ __launch_bounds__(256, 2) void k_gemm1(const bf16* __restrict__ xb, const bf16* __restrict__ w1b,
                                                  const float* __restrict__ b1, bf16* __restrict__ h1,
                                                  float* __restrict__ stats) {
    __shared__ bf16 sA[2 * 128 * 64], sB[2 * 128 * 64];
    int b, m0, n0; tile_coords(blockIdx.x, b, m0, n0);
    f32x4 acc[4][4];
    ZERO_ACC(acc)
    gemm_pipe(xb + ((size_t)(b * V_) + m0) * C_, w1b + n0 * C_, sA, sB, acc);
    int lane = threadIdx.x & 63, wv = threadIdx.x >> 6;
    int wm = (wv & 1) * 64, wn = (wv >> 1) * 64;
    int col = lane & 15, rowq = (lane >> 4) * 4;
    float s = 0.f, ss = 0.f;
#pragma unroll
    for (int ni = 0; ni < 4; ni++) {
        int o = n0 + wn + ni * 16 + col;
        float bias = b1[o];
#pragma unroll
        for (int mi = 0; mi < 4; mi++) {
            size_t vb = (size_t)(b * V_) + m0 + wm + mi * 16 + rowq;
#pragma unroll
            for (int rg = 0; rg < 4; rg++) {
                float val = acc[mi][ni][rg] + bias;
                s += val; ss += val * val;
                h1[(vb + rg) * C_ + o] = (bf16)val;
            }
        }
    }
    s = wave_sum(s); ss = wave_sum(ss);
    if (lane == 0) { atomicAdd(&stats[2 * b], s); atomicAdd(&stats[2 * b + 1], ss); }
}

// =================== P4: GN1 + GELU -> g ===================
__global__ void k_act(const bf16* __restrict__ h1, const float* __restrict__ g1,
                      const float* __restrict__ bt1, const float* __restrict__ stats,
                      bf16* __restrict__ g) {
    int idx = blockIdx.x * 256 + threadIdx.x;   // 2*32768*48 threads
    int cg = idx % 48;
    int t2 = idx / 48;
    int v = t2 & (V_ - 1);
    int b = t2 >> 15;
    float inv  = 1.0f / NTOT;
    float mean = stats[2 * b] * inv;
    float var  = stats[2 * b + 1] * inv - mean * mean;
    float rstd = rsqrtf(var + EPS_);
    int c0 = cg * 8;
    float a[8], be[8];
    {
        const float4 gA = *(const float4*)(g1 + c0);
        const float4 gB = *(const float4*)(g1 + c0 + 4);
        const float4 bA = *(const float4*)(bt1 + c0);
        const float4 bB = *(const float4*)(bt1 + c0 + 4);
        float gg[8] = {gA.x, gA.y, gA.z, gA.w, gB.x, gB.y, gB.z, gB.w};
        float bb[8] = {bA.x, bA.y, bA.z, bA.w, bB.x, bB.y, bB.z, bB.w};
#pragma unroll
        for (int e = 0; e < 8; e++) { a[e] = rstd * gg[e]; be[e] = bb[e] - mean * a[e]; }
    }
    size_t off = ((size_t)b * V_ + v) * C_ + c0;
    bf16x8 xin = *(const bf16x8*)(h1 + off);
    bf16x8 outv;
#pragma unroll
    for (int e = 0; e < 8; e++) outv[e] = (bf16)gelu_t((float)xin[e] * a[e] + be[e]);
    *(bf16x8*)(g + off) = outv;
}

// =================== P5: fused GEMM2 (3 shifted branches) + GN2 stats ===================
// One continuous 18-step (3 branches x 6 K-steps) counted-vmcnt pipeline; shifted-A
// source pointers resolved per unrolled step (validity pre-resolved to a zero page).
__global__ __launch_bounds__(256, 2) void k_gemm2(const bf16* __restrict__ g, const bf16* __restrict__ wb,
                                                  const float* __restrict__ b21, const float* __restrict__ b22,
                                                  const float* __restrict__ b23, bf16* __restrict__ y,
                                                  float* __restrict__ stats, const bf16* __restrict__ zp) {
    __shared__ bf16 sA[2 * 128 * 64], sB[2 * 128 * 64];
    int b, m0, n0; tile_coords(blockIdx.x, b, m0, n0);
    const int tid  = threadIdx.x;
    const int lane = tid & 63, wv = tid >> 6;
    const int wm = (wv & 1) * 64, wn = (wv >> 1) * 64;
    const int col = lane & 15, rowq = (lane >> 4) * 4;
    const int lrow = lane & 15;
    const int q    = lane >> 4;
    const int row_l = tid >> 3;
    const int kcs   = (tid & 7) ^ (row_l & 7);
    const int d0 = m0 >> 10;
    const bf16* gA = g + ((size_t)(b * V_) + m0) * C_;
    const bf16* pc[4];
#pragma unroll
    for (int j = 0; j < 4; j++) pc[j] = gA + (row_l + j * 32) * C_ + kcs * 8;
    const bf16* gb0 = wb + n0 * C_ + row_l * C_ + kcs * 8;
    char* la = (char*)sA + tid * 16;
    char* lb = (char*)sB + tid * 16;
    const char* ra = (const char*)sA;
    const char* rb = (const char*)sB;

    // shifted-A row pointer for step st (ax=st/6, K-group s=st%6), chunk j.
    // s<2 -> +shift group, 2<=s<4 -> center, s>=4 -> -shift group.
    auto aptr = [&](int st, int j) -> const bf16* {
        int ax = st / 6, s = st - ax * 6;
        const bf16* p = pc[j];
        if (s < 2) {
            if (ax == 0)      { int hh = ((m0 >> 5) + j) & 31; p = (hh < 31) ? p + 32 * C_ : zp; }
            else if (ax == 1) { p = (d0 < 31) ? p + 1024 * C_ : zp; }
            else              { p = (row_l < 31) ? p + C_ : zp; }
        } else if (s >= 4) {
            if (ax == 0)      { int hh = ((m0 >> 5) + j) & 31; p = (hh > 0) ? p - 32 * C_ : zp; }
            else if (ax == 1) { p = (d0 > 0) ? p - 1024 * C_ : zp; }
            else              { p = (row_l > 0) ? p - C_ : zp; }
        }
        return p + s * 64;
    };
    auto stage2 = [&](int st, int buf) {
        int ax = st / 6, s = st - ax * 6;
#pragma unroll
        for (int j = 0; j < 4; j++) {
            g2l16(aptr(st, j), la + buf + j * 4096);
            g2l16(gb0 + (ax + 1) * WMAT + s * 64 + j * 32 * C_, lb + buf + j * 4096);
        }
    };

    f32x4 yac[4][4];
    ZERO_ACC(yac)
    f32x4 acc[4][4];
    ZERO_ACC(acc)

    stage2(0, 0);                    // 8 loads in flight
#pragma unroll
    for (int st = 0; st < 18; st++) {
        const int cur = (st & 1) * 16384, nxt = 16384 - cur;
        if (st < 17) {
            stage2(st + 1, nxt);     // +8 loads (16 outstanding)
            VMCNT8();                // cur's 8 landed; nxt's 8 stay in flight
        } else {
            VMCNT0();
        }
        BAR();
#pragma unroll
        for (int t = 0; t < 2; t++) {
            bf16x8 af[4], bfr[4];
#pragma unroll
            for (int i = 0; i < 4; i++) {
                int r = wm + i * 16 + lrow;
                af[i] = *(const bf16x8*)(ra + cur + r * 128 + (((t * 4 + q) ^ (r & 7)) * 16));
            }
#pragma unroll
            for (int i = 0; i < 4; i++) {
                int r = wn + i * 16 + lrow;
                bfr[i] = *(const bf16x8*)(rb + cur + r * 128 + (((t * 4 + q) ^ (r & 7)) * 16));
            }
#pragma unroll
            for (int mi = 0; mi < 4; mi++)
#pragma unroll
                for (int ni = 0; ni < 4; ni++)
                    acc[mi][ni] = __builtin_amdgcn_mfma_f32_16x16x32_bf16(
                        af[mi], bfr[ni], acc[mi][ni], 0, 0, 0);
        }
        if ((st % 6) == 5) {               // end of a branch: fold GELU into yac (regs only)
            int ax = st / 6;
            const float* bs = (ax == 0) ? b21 : (ax == 1) ? b22 : b23;
#pragma unroll
            for (int ni = 0; ni < 4; ni++) {
                float bias = bs[n0 + wn + ni * 16 + col];
#pragma unroll
                for (int mi = 0; mi < 4; mi++)
#pragma unroll
                    for (int rg = 0; rg < 4; rg++) {
                        yac[mi][ni][rg] += gelu_t(acc[mi][ni][rg] + bias);
                        acc[mi][ni][rg] = 0.f;
                    }
            }
        }
        if (st < 17) BAR();
    }

    float s = 0.f, ss = 0.f;
#pragma unroll
    for (int ni = 0; ni < 4; ni++) {
        int o = n0 + wn + ni * 16 + col;
#pragma unroll
        for (int mi = 0; mi < 4; mi++) {
            size_t vb = (size_t)(b * V_) + m0 + wm + mi * 16 + rowq;
#pragma unroll
            for (int rg = 0; rg < 4; rg++) {
                float val = yac[mi][ni][rg];
                s += val; ss += val * val;
                y[(vb + rg) * C_ + o] = (bf16)val;
            }
        }
    }
    s = wave_sum(s); ss = wave_sum(ss);
    if (lane == 0) { atomicAdd(&stats[4 + 2 * b], s); atomicAdd(&stats[5 + 2 * b], ss); }
}

// =================== P6: fold GN2 affine into W3/b3 (per batch) ===================
__global__ void k_fold(const float* __restrict__ w3, const float* __restrict__ b3,
                       const float* __restrict__ g2, const float* __restrict__ bt2,
                       const float* __restrict__ stats, bf16* __restrict__ w3p,
                       float* __restrict__ b3p) {
    int bo = blockIdx.x;           // 768 = 2*384
    int b = bo / 384, o = bo % 384;
    int l = threadIdx.x;           // 64 threads
    float inv  = 1.0f / NTOT;
    float mean = stats[4 + 2 * b] * inv;
    float var  = stats[5 + 2 * b] * inv - mean * mean;
    float rstd = rsqrtf(var + EPS_);
    float part = 0.f;
    for (int c = l; c < C_; c += 64) {
        float wv_ = w3[o * C_ + c];
        float gr  = g2[c] * rstd;
        w3p[(size_t)b * WMAT + o * C_ + c] = (bf16)(wv_ * gr);
        part += wv_ * (bt2[c] - mean * gr);
    }
    part = wave_sum(part);
    if (l == 0) b3p[bo] = b3[o] + part;
}

// =================== P7: GEMM3 -> d_out fp32, channel-first layout ===================
__global__ __launch_bounds__(256, 2) void k_gemm3(const bf16* __restrict__ y, const bf16* __restrict__ w3p,
                                                  const float* __restrict__ b3p, float* __restrict__ out) {
    __shared__ bf16 sA[2 * 128 * 64], sB[2 * 128 * 64];
    int b, m0, n0; tile_coords(blockIdx.x, b, m0, n0);
    f32x4 acc[4][4];
    ZERO_ACC(acc)
    gemm_pipe(y + ((size_t)(b * V_) + m0) * C_, w3p + (size_t)b * WMAT + n0 * C_, sA, sB, acc);
    int lane = threadIdx.x & 63, wv = threadIdx.x >> 6;
    int wm = (wv & 1) * 64, wn = (wv >> 1) * 64;
    int col = lane & 15, rowq = (lane >> 4) * 4;
#pragma unroll
    for (int ni = 0; ni < 4; ni++) {
        int o = n0 + wn + ni * 16 + col;
        float bias = b3p[b * C_ + o];
#pragma unroll
        for (int mi = 0; mi < 4; mi++) {
            f32x4 r = acc[mi][ni];
            r[0] += bias; r[1] += bias; r[2] += bias; r[3] += bias;
            size_t adr = (size_t)b * ((size_t)C_ * V_) + (size_t)o * V_ + (m0 + wm + mi * 16 + rowq);
            *(f32x4*)(out + adr) = r;
        }
    }
}

extern "C" void kernel_launch(void* const* d_in, const int* in_sizes, int n_in,
                              void* d_out, int out_size, void* d_ws, size_t ws_size,
                              hipStream_t stream) {
    const float* x   = (const float*)d_in[0];
    const float* w1  = (const float*)d_in[1];
    const float* b1  = (const float*)d_in[2];
    const float* g1  = (const float*)d_in[3];
    const float* bt1 = (const float*)d_in[4];
    const float* w21 = (const float*)d_in[5];
    const float* b21 = (const float*)d_in[6];
    const float* w22 = (const float*)d_in[7];
    const float* b22 = (const float*)d_in[8];
    const float* w23 = (const float*)d_in[9];
    const float* b23 = (const float*)d_in[10];
    const float* g2  = (const float*)d_in[11];
    const float* bt2 = (const float*)d_in[12];
    const float* w3  = (const float*)d_in[13];
    const float* b3  = (const float*)d_in[14];
    float* out = (float*)d_out;

    char* ws = (char*)d_ws;
    const size_t HALF = 50331648ull;                    // one bf16 tensor (2*384*32768*2 B)
    bf16*  xb  = (bf16*)ws;                             // xb (P2-P3), then y (P5-P7)
    bf16*  g   = (bf16*)(ws + HALF);
    char*  tail = ws + 2 * HALF;
    float* stats = (float*)tail;                        // tail[0:128)   zeroed
    bf16*  zp    = (bf16*)(tail + 2048);                // tail[2048:4096) zeroed
    bf16*  wb    = (bf16*)(tail + 4096);                // 1,179,648 B
    bf16*  w3p   = (bf16*)(tail + 4096 + 1179648);      //   589,824 B
    float* b3p   = (float*)(tail + 4096 + 1179648 + 589824);
    bf16*  h1 = (bf16*)d_out;                           // d_out first half as scratch (dead before P7)
    bf16*  y  = xb;

    hipMemsetAsync(tail, 0, 4096, stream);              // stats + zero page
    k_wcast<<<576,   256, 0, stream>>>(w1, w21, w22, w23, wb);
    k_txp  <<<12288, 256, 0, stream>>>(x, xb);
    k_gemm1<<<1536,  256, 0, stream>>>(xb, wb, b1, h1, stats);
    k_act  <<<12288, 256, 0, stream>>>(h1, g1, bt1, stats, g);
    k_gemm2<<<1536,  256, 0, stream>>>(g, wb, b21, b22, b23, y, stats, zp);
    k_fold <<<768,    64, 0, stream>>>(w3, b3, g2, bt2, stats, w3p, b3p);
    k_gemm3<<<1536,  256, 0, stream>>>(y, w3p, b3p, out);
}

// Round 4
// 400.996 us; speedup vs baseline: 1.5963x; 1.5635x over previous
//
#include <hip/hip_runtime.h>

typedef __bf16 bf16;
typedef __bf16 bf16x8 __attribute__((ext_vector_type(8)));
typedef float  f32x4  __attribute__((ext_vector_type(4)));

#define C_    384
#define V_    32768
#define NTOT  12582912.0f   // 384*32768 elements per batch for GroupNorm
#define EPS_  1e-5f
#define WMAT  147456        // 384*384

// ---- async global->LDS, 16B per lane (per-lane global src address is legal) ----
__device__ __forceinline__ void g2l16(const void* g, void* l) {
    __builtin_amdgcn_global_load_lds(
        (const __attribute__((address_space(1))) void*)g,
        (__attribute__((address_space(3))) void*)l, 16, 0, 0);
}

// NaN-safe tanh-approx GELU: x * 0.5*(1+tanh(t)) = x / (1 + exp(-2t))
__device__ __forceinline__ float gelu_t(float x) {
    float u = -1.5957691216f * x * (1.0f + 0.044715f * x * x);
    return x / (1.0f + __expf(u));
}

__device__ __forceinline__ float wave_sum(float v) {
#pragma unroll
    for (int off = 32; off > 0; off >>= 1) v += __shfl_down(v, off, 64);
    return v;
}

// =================== P1: weights fp32 -> bf16 (w1,w21,w22,w23) ===================
__global__ void k_wcast(const float* __restrict__ w1, const float* __restrict__ w21,
                        const float* __restrict__ w22, const float* __restrict__ w23,
                        bf16* __restrict__ wb) {
    int i = (blockIdx.x * 256 + threadIdx.x) * 4;
    const float* srcs[4] = {w1, w21, w22, w23};
    int t = i / WMAT;
    int j = i - t * WMAT;
    const float4 v = *(const float4*)(srcs[t] + j);
    bf16* d = wb + i;
    d[0] = (bf16)v.x; d[1] = (bf16)v.y; d[2] = (bf16)v.z; d[3] = (bf16)v.w;
}

// =================== P2: x [b][c][v] fp32 -> xb [b][v][c] bf16 ===================
__global__ void k_txp(const float* __restrict__ x, bf16* __restrict__ xb) {
    __shared__ float tile[32][65];
    int bid = blockIdx.x;                   // 2 * 512 * 12
    int cb = bid % 12;
    int vb = (bid / 12) & 511;
    int b  = bid / (12 * 512);
    int c0 = cb * 32, v0 = vb * 64;
    int t = threadIdx.x;
    int vl = t & 63, cl = t >> 6;
    const float* src = x + ((size_t)(b * C_ + c0)) * V_ + v0;
#pragma unroll
    for (int i = 0; i < 8; i++)
        tile[cl + i * 4][vl] = src[(size_t)(cl + i * 4) * V_ + vl];
    __syncthreads();
    int vl2 = t >> 2, cl2 = (t & 3) * 8;
    bf16x8 o;
#pragma unroll
    for (int j = 0; j < 8; j++) o[j] = (bf16)tile[cl2 + j][vl2];
    *(bf16x8*)(xb + ((size_t)(b * V_ + v0 + vl2)) * C_ + c0 + cl2) = o;
}

// XCD-aware tile map: bid&7 ~ XCD; each XCD owns a contiguous 64-m-tile range,
// n fastest so the 3 n-blocks of one m-tile are temporally adjacent on one XCD.
__device__ __forceinline__ void tile_coords(int bid, int& b, int& m0, int& n0) {
    int x = bid & 7, gq = bid >> 3;        // gq in [0,192)
    n0 = (gq % 3) * 128;
    int mt = x * 64 + gq / 3;              // 512 m-tiles (2 batches x 256)
    b  = mt >> 8;
    m0 = (mt & 255) * 128;
}

#define ZERO_ACC42(acc) \
    _Pragma("unroll") for (int i = 0; i < 4; i++) \
    _Pragma("unroll") for (int j = 0; j < 2; j++) \
    _Pragma("unroll") for (int r = 0; r < 4; r++) acc[i][j][r] = 0.f;

// ---- counted waits + barrier-with-compiler-fence (never drain vmcnt to 0 in loop)
#define VMCNT4() asm volatile("s_waitcnt vmcnt(4)" ::: "memory")
#define VMCNT0() asm volatile("s_waitcnt vmcnt(0)" ::: "memory")
#define BAR()    asm volatile("s_barrier" ::: "memory")

// =================== Pipelined MFMA GEMM core: 128x128 tile, 512 thr / 8 waves ======
// Per-wave output 64x32 (acc[4][2]) -> half the accumulator registers of the 4-wave
// version; target 4 waves/SIMD (2 blocks/CU co-resident, 16 waves/CU).
// Double-buffered LDS (2 x 16KB per operand), counted vmcnt(4), XOR-swizzled rows:
// LDS [128 rows][64 ch]; 16B chunk c of row r holds global chunk c^(r&7).
__device__ __forceinline__ void gemm_pipe(const bf16* __restrict__ A, const bf16* __restrict__ Bw,
                                          bf16* sA, bf16* sB, f32x4 acc[4][2]) {
    const int tid  = threadIdx.x;
    const int lane = tid & 63;
    const int wv   = tid >> 6;                       // 0..7
    const int wm   = (wv & 1) * 64, wn = (wv >> 1) * 32;
    const int lrow = lane & 15;
    const int q    = lane >> 4;
    const int row_l = tid >> 3;                      // 0..63
    const int kcs   = (tid & 7) ^ (row_l & 7);
    const bf16* ga = A  + row_l * C_ + kcs * 8;
    const bf16* gb = Bw + row_l * C_ + kcs * 8;
    char* la = (char*)sA + tid * 16;                 // 512 thr x 16B = 8KB per instr
    char* lb = (char*)sB + tid * 16;
    const char* ra = (const char*)sA;
    const char* rb = (const char*)sB;
    // prologue: stage K-step 0 into buffer 0 (4 loads in flight)
#pragma unroll
    for (int j = 0; j < 2; j++) {
        g2l16(ga + j * 64 * C_, la + j * 8192);
        g2l16(gb + j * 64 * C_, lb + j * 8192);
    }
#pragma unroll
    for (int s = 0; s < 6; s++) {
        const int cur = (s & 1) * 16384, nxt = 16384 - cur;
        if (s < 5) {
            int off = (s + 1) * 64;
#pragma unroll
            for (int j = 0; j < 2; j++) {
                g2l16(ga + off + j * 64 * C_, la + nxt + j * 8192);
                g2l16(gb + off + j * 64 * C_, lb + nxt + j * 8192);
            }
            VMCNT4();
        } else {
            VMCNT0();
        }
        BAR();
#pragma unroll
        for (int t = 0; t < 2; t++) {
            bf16x8 af[4], bfr[2];
#pragma unroll
            for (int i = 0; i < 4; i++) {
                int r = wm + i * 16 + lrow;
                af[i] = *(const bf16x8*)(ra + cur + r * 128 + (((t * 4 + q) ^ (r & 7)) * 16));
            }
#pragma unroll
            for (int i = 0; i < 2; i++) {
                int r = wn + i * 16 + lrow;
                bfr[i] = *(const bf16x8*)(rb + cur + r * 128 + (((t * 4 + q) ^ (r & 7)) * 16));
            }
#pragma unroll
            for (int mi = 0; mi < 4; mi++)
#pragma unroll
                for (int ni = 0; ni < 2; ni++)
                    acc[mi][ni] = __builtin_amdgcn_mfma_f32_16x16x32_bf16(
                        af[mi], bfr[ni], acc[mi][ni], 0, 0, 0);
        }
        if (s < 5) BAR();
    }
}

// =================== P3: GEMM1 = xb @ w1 + b1 -> h1 bf16, + GN1 stats ===================
__global__ __launch_bounds__(512, 4) void k_gemm1(const bf16* __restrict__ xb, const bf16* __restrict__ w1b,
                                                  const float* __restrict__ b1, bf16* __restrict__ h1,
                                                  float* __restrict__ stats) {
    __shared__ bf16 sA[2 * 128 * 64], sB[2 * 128 * 64];
    __shared__ float sred[16];
    int b, m0, n0; tile_coords(blockIdx.x, b, m0, n0);
    f32x4 acc[4][2];
    ZERO_ACC42(acc)
    gemm_pipe(xb + ((size_t)(b * V_) + m0) * C_, w1b + n0 * C_, sA, sB, acc);
    int lane = threadIdx.x & 63, wv = threadIdx.x >> 6;
    int wm = (wv & 1) * 64, wn = (wv >> 1) * 32;
    int col = lane & 15, rowq = (lane >> 4) * 4;
    float s = 0.f, ss = 0.f;
#pragma unroll
    for (int ni = 0; ni < 2; ni++) {
        int o = n0 + wn + ni * 16 + col;
        float bias = b1[o];
#pragma unroll
        for (int mi = 0; mi < 4; mi++) {
            size_t vb = (size_t)(b * V_) + m0 + wm + mi * 16 + rowq;
#pragma unroll
            for (int rg = 0; rg < 4; rg++) {
                float val = acc[mi][ni][rg] + bias;
                s += val; ss += val * val;
                h1[(vb + rg) * C_ + o] = (bf16)val;
            }
        }
    }
    s = wave_sum(s); ss = wave_sum(ss);
    if (lane == 0) { sred[wv] = s; sred[8 + wv] = ss; }
    __syncthreads();
    if (threadIdx.x == 0) {
        float S = 0.f, SS = 0.f;
#pragma unroll
        for (int i = 0; i < 8; i++) { S += sred[i]; SS += sred[8 + i]; }
        atomicAdd(&stats[2 * b], S); atomicAdd(&stats[2 * b + 1], SS);
    }
}

// =================== P4: GN1 + GELU -> g ===================
__global__ void k_act(const bf16* __restrict__ h1, const float* __restrict__ g1,
                      const float* __restrict__ bt1, const float* __restrict__ stats,
                      bf16* __restrict__ g) {
    int idx = blockIdx.x * 256 + threadIdx.x;   // 2*32768*48 threads
    int cg = idx % 48;
    int t2 = idx / 48;
    int v = t2 & (V_ - 1);
    int b = t2 >> 15;
    float inv  = 1.0f / NTOT;
    float mean = stats[2 * b] * inv;
    float var  = stats[2 * b + 1] * inv - mean * mean;
    float rstd = rsqrtf(var + EPS_);
    int c0 = cg * 8;
    float a[8], be[8];
    {
        const float4 gA = *(const float4*)(g1 + c0);
        const float4 gB = *(const float4*)(g1 + c0 + 4);
        const float4 bA = *(const float4*)(bt1 + c0);
        const float4 bB = *(const float4*)(bt1 + c0 + 4);
        float gg[8] = {gA.x, gA.y, gA.z, gA.w, gB.x, gB.y, gB.z, gB.w};
        float bb[8] = {bA.x, bA.y, bA.z, bA.w, bB.x, bB.y, bB.z, bB.w};
#pragma unroll
        for (int e = 0; e < 8; e++) { a[e] = rstd * gg[e]; be[e] = bb[e] - mean * a[e]; }
    }
    size_t off = ((size_t)b * V_ + v) * C_ + c0;
    bf16x8 xin = *(const bf16x8*)(h1 + off);
    bf16x8 outv;
#pragma unroll
    for (int e = 0; e < 8; e++) outv[e] = (bf16)gelu_t((float)xin[e] * a[e] + be[e]);
    *(bf16x8*)(g + off) = outv;
}

// =================== P5: fused GEMM2 (3 shifted branches) + GN2 stats ===================
// 18-step (3 branches x 6 K-steps) counted-vmcnt pipeline, 512 threads.
// Shifted-A validity resolved PER LANE to a zero page (global src of
// global_load_lds is per-lane; only the LDS dest must be linear).
__global__ __launch_bounds__(512, 4) void k_gemm2(const bf16* __restrict__ g, const bf16* __restrict__ wb,
                                                  const float* __restrict__ b21, const float* __restrict__ b22,
                                                  const float* __restrict__ b23, bf16* __restrict__ y,
                                                  float* __restrict__ stats, const bf16* __restrict__ zp) {
    __shared__ bf16 sA[2 * 128 * 64], sB[2 * 128 * 64];
    __shared__ float sred[16];
    int b, m0, n0; tile_coords(blockIdx.x, b, m0, n0);
    const int tid  = threadIdx.x;
    const int lane = tid & 63, wv = tid >> 6;
    const int wm = (wv & 1) * 64, wn = (wv >> 1) * 32;
    const int col = lane & 15, rowq = (lane >> 4) * 4;
    const int lrow = lane & 15;
    const int q    = lane >> 4;
    const int row_l = tid >> 3;                      // 0..63
    const int kcs   = (tid & 7) ^ (row_l & 7);
    const int d0    = m0 >> 10;                      // uniform over tile
    const int hbase = (m0 >> 5) & 31;                // h of row 0 (tile spans h..h+3)
    const int wpos  = row_l & 31;                    // w of row (j*64 preserves mod 32)
    const bf16* gA = g + ((size_t)(b * V_) + m0) * C_;
    const bf16* gb0 = wb + n0 * C_ + row_l * C_ + kcs * 8;
    char* la = (char*)sA + tid * 16;
    char* lb = (char*)sB + tid * 16;
    const char* ra = (const char*)sA;
    const char* rb = (const char*)sB;

    // stage K-step st (ax = st/6 branch, s = st%6 K-group) into LDS buffer `buf`.
    // s<2: +shift rows, 2<=s<4: center, s>=4: -shift rows; invalid lanes read zp.
    auto stage2 = [&](int st, int buf) {
        int ax = st / 6, s = st - ax * 6;
#pragma unroll
        for (int j = 0; j < 2; j++) {
            int row = j * 64 + row_l;
            const bf16* p = gA + row * C_ + kcs * 8;
            if (s < 2) {
                bool v; int sh;
                if (ax == 0)      { v = (hbase + (row >> 5)) < 31; sh = 32 * C_; }
                else if (ax == 1) { v = d0 < 31;                   sh = 1024 * C_; }
                else              { v = wpos < 31;                 sh = C_; }
                p = v ? p + sh : zp;
            } else if (s >= 4) {
                bool v; int sh;
                if (ax == 0)      { v = (hbase + (row >> 5)) > 0;  sh = 32 * C_; }
                else if (ax == 1) { v = d0 > 0;                    sh = 1024 * C_; }
                else              { v = wpos > 0;                  sh = C_; }
                p = v ? p - sh : zp;
            }
            g2l16(p + s * 64, la + buf + j * 8192);
            g2l16(gb0 + (ax + 1) * WMAT + s * 64 + j * 64 * C_, lb + buf + j * 8192);
        }
    };

    f32x4 yac[4][2];
    ZERO_ACC42(yac)
    f32x4 acc[4][2];
    ZERO_ACC42(acc)

    stage2(0, 0);                    // 4 loads in flight
#pragma unroll
    for (int st = 0; st < 18; st++) {
        const int cur = (st & 1) * 16384, nxt = 16384 - cur;
        if (st < 17) {
            stage2(st + 1, nxt);     // +4 loads (8 outstanding)
            VMCNT4();                // cur's 4 landed; nxt's 4 stay in flight
        } else {
            VMCNT0();
        }
        BAR();
#pragma unroll
        for (int t = 0; t < 2; t++) {
            bf16x8 af[4], bfr[2];
#pragma unroll
            for (int i = 0; i < 4; i++) {
                int r = wm + i * 16 + lrow;
                af[i] = *(const bf16x8*)(ra + cur + r * 128 + (((t * 4 + q) ^ (r & 7)) * 16));
            }
#pragma unroll
            for (int i = 0; i < 2; i++) {
                int r = wn + i * 16 + lrow;
                bfr[i] = *(const bf16x8*)(rb + cur + r * 128 + (((t * 4 + q) ^ (r & 7)) * 16));
            }
#pragma unroll
            for (int mi = 0; mi < 4; mi++)
#pragma unroll
                for (int ni = 0; ni < 2; ni++)
                    acc[mi][ni] = __builtin_amdgcn_mfma_f32_16x16x32_bf16(
                        af[mi], bfr[ni], acc[mi][ni], 0, 0, 0);
        }
        if ((st % 6) == 5) {               // end of a branch: fold GELU into yac (regs only)
            int ax = st / 6;
            const float* bs = (ax == 0) ? b21 : (ax == 1) ? b22 : b23;
#pragma unroll
            for (int ni = 0; ni < 2; ni++) {
                float bias = bs[n0 + wn + ni * 16 + col];
#pragma unroll
                for (int mi = 0; mi < 4; mi++)
#pragma unroll
                    for (int rg = 0; rg < 4; rg++) {
                        yac[mi][ni][rg] += gelu_t(acc[mi][ni][rg] + bias);
                        acc[mi][ni][rg] = 0.f;
                    }
            }
        }
        if (st < 17) BAR();
    }

    float s = 0.f, ss = 0.f;
#pragma unroll
    for (int ni = 0; ni < 2; ni++) {
        int o = n0 + wn + ni * 16 + col;
#pragma unroll
        for (int mi = 0; mi < 4; mi++) {
            size_t vb = (size_t)(b * V_) + m0 + wm + mi * 16 + rowq;
#pragma unroll
            for (int rg = 0; rg < 4; rg++) {
                float val = yac[mi][ni][rg];
                s += val; ss += val * val;
                y[(vb + rg) * C_ + o] = (bf16)val;
            }
        }
    }
    s = wave_sum(s); ss = wave_sum(ss);
    if (lane == 0) { sred[wv] = s; sred[8 + wv] = ss; }
    __syncthreads();
    if (tid == 0) {
        float S = 0.f, SS = 0.f;
#pragma unroll
        for (int i = 0; i < 8; i++) { S += sred[i]; SS += sred[8 + i]; }
        atomicAdd(&stats[4 + 2 * b], S); atomicAdd(&stats[5 + 2 * b], SS);
    }
}

// =================== P6: fold GN2 affine into W3/b3 (per batch) ===================
__global__ void k_fold(const float* __restrict__ w3, const float* __restrict__ b3,
                       const float* __restrict__ g2, const float* __restrict__ bt2,
                       const float* __restrict__ stats, bf16* __restrict__ w3p,
                       float* __restrict__ b3p) {
    int bo = blockIdx.x;           // 768 = 2*384
    int b = bo / 384, o = bo % 384;
    int l = threadIdx.x;           // 64 threads
    float inv  = 1.0f / NTOT;
    float mean = stats[4 + 2 * b] * inv;
    float var  = stats[5 + 2 * b] * inv - mean * mean;
    float rstd = rsqrtf(var + EPS_);
    float part = 0.f;
    for (int c = l; c < C_; c += 64) {
        float wv_ = w3[o * C_ + c];
        float gr  = g2[c] * rstd;
        w3p[(size_t)b * WMAT + o * C_ + c] = (bf16)(wv_ * gr);
        part += wv_ * (bt2[c] - mean * gr);
    }
    part = wave_sum(part);
    if (l == 0) b3p[bo] = b3[o] + part;
}

// =================== P7: GEMM3 -> d_out fp32, channel-first layout ===================
__global__ __launch_bounds__(512, 4) void k_gemm3(const bf16* __restrict__ y, const bf16* __restrict__ w3p,
                                                  const float* __restrict__ b3p, float* __restrict__ out) {
    __shared__ bf16 sA[2 * 128 * 64], sB[2 * 128 * 64];
    int b, m0, n0; tile_coords(blockIdx.x, b, m0, n0);
    f32x4 acc[4][2];
    ZERO_ACC42(acc)
    gemm_pipe(y + ((size_t)(b * V_) + m0) * C_, w3p + (size_t)b * WMAT + n0 * C_, sA, sB, acc);
    int lane = threadIdx.x & 63, wv = threadIdx.x >> 6;
    int wm = (wv & 1) * 64, wn = (wv >> 1) * 32;
    int col = lane & 15, rowq = (lane >> 4) * 4;
#pragma unroll
    for (int ni = 0; ni < 2; ni++) {
        int o = n0 + wn + ni * 16 + col;
        float bias = b3p[b * C_ + o];
#pragma unroll
        for (int mi = 0; mi < 4; mi++) {
            f32x4 r = acc[mi][ni];
            r[0] += bias; r[1] += bias; r[2] += bias; r[3] += bias;
            size_t adr = (size_t)b * ((size_t)C_ * V_) + (size_t)o * V_ + (m0 + wm + mi * 16 + rowq);
            *(f32x4*)(out + adr) = r;
        }
    }
}

extern "C" void kernel_launch(void* const* d_in, const int* in_sizes, int n_in,
                              void* d_out, int out_size, void* d_ws, size_t ws_size,
                              hipStream_t stream) {
    const float* x   = (const float*)d_in[0];
    const float* w1  = (const float*)d_in[1];
    const float* b1  = (const float*)d_in[2];
    const float* g1  = (const float*)d_in[3];
    const float* bt1 = (const float*)d_in[4];
    const float* w21 = (const float*)d_in[5];
    const float* b21 = (const float*)d_in[6];
    const float* w22 = (const float*)d_in[7];
    const float* b22 = (const float*)d_in[8];
    const float* w23 = (const float*)d_in[9];
    const float* b23 = (const float*)d_in[10];
    const float* g2  = (const float*)d_in[11];
    const float* bt2 = (const float*)d_in[12];
    const float* w3  = (const float*)d_in[13];
    const float* b3  = (const float*)d_in[14];
    float* out = (float*)d_out;

    char* ws = (char*)d_ws;
    const size_t HALF = 50331648ull;                    // one bf16 tensor (2*384*32768*2 B)
    bf16*  xb  = (bf16*)ws;                             // xb (P2-P3), then y (P5-P7)
    bf16*  g   = (bf16*)(ws + HALF);
    char*  tail = ws + 2 * HALF;
    float* stats = (float*)tail;                        // tail[0:128)   zeroed
    bf16*  zp    = (bf16*)(tail + 2048);                // tail[2048:4096) zeroed
    bf16*  wb    = (bf16*)(tail + 4096);                // 1,179,648 B
    bf16*  w3p   = (bf16*)(tail + 4096 + 1179648);      //   589,824 B
    float* b3p   = (float*)(tail + 4096 + 1179648 + 589824);
    bf16*  h1 = (bf16*)d_out;                           // d_out first half as scratch (dead before P7)
    bf16*  y  = xb;

    hipMemsetAsync(tail, 0, 4096, stream);              // stats + zero page
    k_wcast<<<576,   256, 0, stream>>>(w1, w21, w22, w23, wb);
    k_txp  <<<12288, 256, 0, stream>>>(x, xb);
    k_gemm1<<<1536,  512, 0, stream>>>(xb, wb, b1, h1, stats);
    k_act  <<<12288, 256, 0, stream>>>(h1, g1, bt1, stats, g);
    k_gemm2<<<1536,  512, 0, stream>>>(g, wb, b21, b22, b23, y, stats, zp);
    k_fold <<<768,    64, 0, stream>>>(w3, b3, g2, bt2, stats, w3p, b3p);
    k_gemm3<<<1536,  512, 0, stream>>>(y, w3p, b3p, out);
}